// Round 4
// baseline (306.706 us; speedup 1.0000x reference)
//
#include <hip/hip_runtime.h>
#include <math.h>

typedef float f32x2 __attribute__((ext_vector_type(2)));

// ---- d_ws layout (float indices), all pair-bases 8B-aligned ----
#define WS_R    0      // R[2][20] = rel factors
#define WS_HW   40     // hid_W[20][20]
#define WS_HB   440    // hid_b[20]
#define WS_MW   460    // merge_W[20]
#define WS_MB   480    // merge_b
#define WS_B0   482    // base[2][16]
#define WS_Z0   514    // zvec[2][16]
#define WS_W4P  546    // W4pk[8][4] f32x2 = 64 floats: [j][k] = {W4[2j][k], W4[2j+1][k]}
#define WS_DW   610    // d_W[4]
#define WS_DB   614    // d_b[4]
#define WS_WUP  618    // Wupk[16][10] f32x2 = 320: [h][j] = {Wu[2j][h], Wu[2j+1][h]}
#define WS_WVP  938    // Wvpk[16][10] f32x2 = 320
#define WS_UB   1258   // lane_conv_b[20]
#define WS_PM   1278   // int pmask[8]
// total 1286 floats

__global__ void frap_setup(
    const int* __restrict__ p2m, const int* __restrict__ comp_mask,
    const float* __restrict__ p_emb, const float* __restrict__ d_W, const float* __restrict__ d_b,
    const float* __restrict__ lane_W, const float* __restrict__ lane_b,
    const float* __restrict__ lane_conv_W, const float* __restrict__ lane_conv_b,
    const float* __restrict__ rel_emb, const float* __restrict__ rel_conv_W, const float* __restrict__ rel_conv_b,
    const float* __restrict__ hid_W, const float* __restrict__ hid_b,
    const float* __restrict__ merge_W, const float* __restrict__ merge_b,
    float* __restrict__ ws)
{
    const int t = threadIdx.x;
    const int NTH = 256;
    // R[c][o] = relu(rel_conv(relu(rel_emb[c])))
    for (int i = t; i < 40; i += NTH) {
        int c = i / 20, o = i % 20;
        float s = rel_conv_b[o];
        #pragma unroll
        for (int k = 0; k < 4; ++k)
            s = fmaf(rel_conv_W[o*4+k], fmaxf(rel_emb[c*4+k], 0.f), s);
        ws[WS_R + i] = fmaxf(s, 0.f);
    }
    for (int i = t; i < 400; i += NTH) ws[WS_HW + i] = hid_W[i];
    for (int i = t; i < 20; i += NTH) {
        ws[WS_HB + i] = hid_b[i];
        ws[WS_MW + i] = merge_W[i];
        ws[WS_UB + i] = lane_conv_b[i];
    }
    if (t == 0) { ws[WS_MB] = merge_b[0]; ws[WS_MB + 1] = 0.f; }
    // base/zvec
    for (int i = t; i < 32; i += NTH) {
        int c = i >> 4, h = i & 15;
        float s = lane_b[h];
        #pragma unroll
        for (int k = 0; k < 4; ++k) {
            float sg = 1.f/(1.f + __expf(-p_emb[c*4+k]));
            s = fmaf(lane_W[h*8+4+k], sg, s);
        }
        ws[WS_B0 + c*16 + h] = s;
        float z = s;
        #pragma unroll
        for (int k = 0; k < 4; ++k) {
            float sg = 1.f/(1.f + __expf(-d_b[k]));
            z = fmaf(lane_W[h*8+k], sg, z);
        }
        ws[WS_Z0 + c*16 + h] = fmaxf(z, 0.f);
    }
    // W4pk: i = (j*4+k)*2+s
    for (int i = t; i < 64; i += NTH) {
        int s = i & 1, k = (i >> 1) & 3, j = i >> 3;
        ws[WS_W4P + i] = lane_W[(2*j + s)*8 + k];
    }
    if (t < 4) { ws[WS_DW + t] = d_W[t]; ws[WS_DB + t] = d_b[t]; }
    // Wu/Wv pk: i = (h*10+j)*2+s
    for (int i = t; i < 320; i += NTH) {
        int s = i & 1, j = (i >> 1) % 10, h = i / 20;
        ws[WS_WUP + i] = lane_conv_W[(2*j + s)*32 + h];
        ws[WS_WVP + i] = lane_conv_W[(2*j + s)*32 + 16 + h];
    }
    int* wi = (int*)ws;
    for (int i = t; i < 8; i += NTH) {
        int mk = 0;
        for (int m = 0; m < 12; ++m) mk |= (p2m[i*12 + m] & 1) << m;
        wi[WS_PM + i] = mk;
    }
}

__global__ __launch_bounds__(512, 4) void frap_main(
    const float* __restrict__ states, const int* __restrict__ comp_mask,
    const float* __restrict__ ws, float* __restrict__ out, int B)
{
    __shared__ float v_s[8*64*20];                 // 40,960 B
    const int tid  = threadIdx.x;
    const int lane = tid & 63;
    const int p    = __builtin_amdgcn_readfirstlane(tid >> 6);  // wave-uniform
    const int b    = blockIdx.x * 64 + lane;
    const int bc   = b < B ? b : B - 1;
    const int* wi  = (const int*)ws;
    const f32x2 zero2 = {0.f, 0.f};

    const float* srow = states + (size_t)bc * 13;
    const int cmask = wi[WS_PM + (int)srow[0]];    // lane-varying
    float dm[12];
    #pragma unroll
    for (int m = 0; m < 12; ++m) dm[m] = srow[1+m];

    const int pmask = wi[WS_PM + p];               // scalar

    // ---- stage 1: agg as 8 f32x2
    const int notp = ~pmask & 0xFFF;
    const float cnt1 = (float)__popc(cmask & notp);
    const float cnt0 = (float)__popc(~cmask & notp);

    f32x2 agg[8];
    {
        const f32x2* Z2 = (const f32x2*)(ws + WS_Z0);
        f32x2 c0 = {cnt0, cnt0}, c1 = {cnt1, cnt1};
        #pragma unroll
        for (int j = 0; j < 8; ++j)
            agg[j] = __builtin_elementwise_fma(c1, Z2[8+j], c0 * Z2[j]);
    }
    {
        const f32x2* W4P = (const f32x2*)(ws + WS_W4P);
        const f32x2* B2  = (const f32x2*)(ws + WS_B0);
        #pragma unroll
        for (int m = 0; m < 12; ++m) {
            if ((pmask >> m) & 1) {                // wave-uniform branch
                const bool cbit = (cmask >> m) & 1;
                f32x2 eb[4];
                #pragma unroll
                for (int k = 0; k < 4; ++k) {
                    float xx = fmaf(dm[m], ws[WS_DW+k], ws[WS_DB+k]);
                    float e = __builtin_amdgcn_rcpf(1.f + __expf(-xx));
                    eb[k][0] = e; eb[k][1] = e;
                }
                #pragma unroll
                for (int j = 0; j < 8; ++j) {
                    f32x2 tt = cbit ? B2[8+j] : B2[j];
                    #pragma unroll
                    for (int k = 0; k < 4; ++k)
                        tt = __builtin_elementwise_fma(W4P[j*4+k], eb[k], tt);
                    agg[j] += __builtin_elementwise_max(tt, zero2);
                }
            }
        }
    }

    // ---- stage 2: u2 (regs) + v2 -> LDS
    f32x2 u2[10], v2[10];
    {
        const f32x2* UB2 = (const f32x2*)(ws + WS_UB);
        const f32x2* WUP = (const f32x2*)(ws + WS_WUP);
        const f32x2* WVP = (const f32x2*)(ws + WS_WVP);
        #pragma unroll
        for (int j = 0; j < 10; ++j) { u2[j] = UB2[j]; v2[j] = zero2; }
        #pragma unroll
        for (int h = 0; h < 16; ++h) {
            float ah = agg[h >> 1][h & 1];
            f32x2 ab = {ah, ah};
            #pragma unroll
            for (int j = 0; j < 10; ++j) {
                u2[j] = __builtin_elementwise_fma(WUP[h*10+j], ab, u2[j]);
                v2[j] = __builtin_elementwise_fma(WVP[h*10+j], ab, v2[j]);
            }
        }
        float* vdst = &v_s[tid * 20];
        #pragma unroll
        for (int j = 0; j < 10; ++j)
            *(f32x2*)(vdst + 2*j) = v2[j];
    }
    __syncthreads();

    // ---- stage 3: y = relu(u+v_j)*R_c ; s = hid_W·y ; q += mw·relu(s)
    float q_acc = 7.f * ws[WS_MB];
    const f32x2* H2 = (const f32x2*)(ws + WS_HW);
    for (int qi = 0; qi < 7; ++qi) {
        const int j  = qi + (qi >= p ? 1 : 0);              // scalar
        const int cf = comp_mask[p*7 + qi];                 // scalar
        const f32x2* R2  = (const f32x2*)(ws + WS_R + cf*20);
        const f32x2* vj2 = (const f32x2*)&v_s[(j*64 + lane)*20];
        f32x2 y2[10];
        #pragma unroll
        for (int jj = 0; jj < 10; ++jj)
            y2[jj] = __builtin_elementwise_max(u2[jj] + vj2[jj], zero2) * R2[jj];
        #pragma unroll
        for (int o2 = 0; o2 < 20; ++o2) {
            f32x2 acc = zero2;
            #pragma unroll
            for (int jj = 0; jj < 10; ++jj)
                acc = __builtin_elementwise_fma(H2[o2*10+jj], y2[jj], acc);
            float s = acc[0] + acc[1] + ws[WS_HB + o2];
            q_acc = fmaf(ws[WS_MW + o2], fmaxf(s, 0.f), q_acc);
        }
    }
    if (b < B) out[(size_t)b*8 + p] = q_acc;
}

extern "C" void kernel_launch(void* const* d_in, const int* in_sizes, int n_in,
                              void* d_out, int out_size, void* d_ws, size_t ws_size,
                              hipStream_t stream) {
    const float* states       = (const float*)d_in[0];
    const int*   p2m          = (const int*)  d_in[1];
    const int*   comp_mask    = (const int*)  d_in[3];
    const float* p_emb        = (const float*)d_in[4];
    const float* d_W          = (const float*)d_in[5];
    const float* d_b          = (const float*)d_in[6];
    const float* lane_W       = (const float*)d_in[7];
    const float* lane_b       = (const float*)d_in[8];
    const float* lane_conv_W  = (const float*)d_in[9];
    const float* lane_conv_b  = (const float*)d_in[10];
    const float* rel_emb      = (const float*)d_in[11];
    const float* rel_conv_W   = (const float*)d_in[12];
    const float* rel_conv_b   = (const float*)d_in[13];
    const float* hid_W        = (const float*)d_in[14];
    const float* hid_b        = (const float*)d_in[15];
    const float* merge_W      = (const float*)d_in[16];
    const float* merge_b      = (const float*)d_in[17];
    float* out = (float*)d_out;
    float* ws  = (float*)d_ws;

    frap_setup<<<1, 256, 0, stream>>>(p2m, comp_mask, p_emb, d_W, d_b, lane_W, lane_b,
        lane_conv_W, lane_conv_b, rel_emb, rel_conv_W, rel_conv_b, hid_W, hid_b,
        merge_W, merge_b, ws);

    int B = in_sizes[0] / 13;
    int grid = (B + 63) / 64;
    frap_main<<<grid, 512, 0, stream>>>(states, comp_mask, ws, out, B);
}